// Round 5
// baseline (402.187 us; speedup 1.0000x reference)
//
#include <hip/hip_runtime.h>
#include <hip/hip_bf16.h>

#define BB 64
#define LCC 512
#define LQQ 64
#define DDD 256

typedef short bf16x8 __attribute__((ext_vector_type(8)));
typedef float f32x4 __attribute__((ext_vector_type(4)));
typedef unsigned u32x4 __attribute__((ext_vector_type(4)));

// HW packed conversion: 2 floats -> 2 bf16 in one v_cvt_pk_bf16_f32 (gfx950).
static __device__ __forceinline__ unsigned pk2bf(float a, float b) {
  __hip_bfloat162 h = __float22bfloat162_rn(make_float2(a, b));
  unsigned u;
  __builtin_memcpy(&u, &h, sizeof(u));
  return u;
}
static __device__ __forceinline__ unsigned short bf1(float f) {
  __hip_bfloat16 h = __float2bfloat16(f);
  unsigned short u;
  __builtin_memcpy(&u, &h, sizeof(u));
  return u;
}

static __device__ __forceinline__ void nt_store4(float* p, float a, float b, float c, float d) {
  f32x4 v = { a, b, c, d };
  __builtin_nontemporal_store(v, (f32x4*)p);
}

// Per-batch release: all threads fence, then one thread bumps the counter.
static __device__ __forceinline__ void signal_cnt(int* c, int tid) {
  __threadfence();
  __syncthreads();
  if (tid == 0)
    __hip_atomic_fetch_add(c, 1, __ATOMIC_RELEASE, __HIP_MEMORY_SCOPE_AGENT);
}
// Bounded spin (fail-visible, never hangs): tid0 polls, block barriers after.
static __device__ __forceinline__ void wait_cnt(int* c, int target) {
  int n = 0;
  while (__hip_atomic_load(c, __ATOMIC_ACQUIRE, __HIP_MEMORY_SCOPE_AGENT) < target) {
    __builtin_amdgcn_s_sleep(8);
    if (++n > (1 << 20)) break;
  }
}

// ---------------------------------------------------------------------------
// Fused kernel: 512 blocks = 64 batches x 8 slots; 256 threads (4 waves).
// Per-batch phase pipeline with device-scope arrival counters:
//   phase1 (slot=LC-tile): E tile -> P (rowsum-scaled), Et, csp  -> cnt1[b]++
//   phase2 (slot=D-slice): wait cnt1[b]==8; T = diag(1/cs) Et @ cx -> Tt, Qt
//                                                                 -> cnt2[b]++
//   phase3 (slot=LC-tile): wait cnt2[b]==8; A=P@qu, Bm=P@T -> out (all 4 chunks)
// Batches pipeline across the GPU; no grid-wide drains.
// LDS: 54 KiB union -> 2 blocks/CU. Deadlock-free: waits are intra-batch only
// and a batch's 8 blocks are contiguous IDs (dispatched together).
// ---------------------------------------------------------------------------
__global__ __launch_bounds__(256, 2) void fused(
    const float* __restrict__ cx, const float* __restrict__ qu,
    const float* __restrict__ W, const float* __restrict__ Wb,
    unsigned short* __restrict__ P, unsigned short* __restrict__ Et,
    float* __restrict__ csp, unsigned short* __restrict__ Qt,
    unsigned short* __restrict__ Tt, float* __restrict__ out,
    int* __restrict__ cnt1, int* __restrict__ cnt2)
{
  __shared__ __align__(16) char smem[54016];

  const int tid = threadIdx.x;
  const int b = blockIdx.x >> 3;
  const int s = blockIdx.x & 7;
  const int w = tid >> 6, lane = tid & 63, quad = lane >> 4, ln = lane & 15;

  // ======================= phase 1: scores (tile = s) =======================
  {
    float* w_lds          = (float*)(smem);                 // 768 f
    unsigned short* Bs    = (unsigned short*)(smem + 3072); // 64*264 us
    float* E_lds          = (float*)(smem + 36864);         // 64*65 f
    float* sc_lds         = (float*)(smem + 53504);         // 64 f
    float* sq_lds         = (float*)(smem + 53760);         // 64 f
    const int i0 = s * 64;

    for (int idx = tid; idx < 768; idx += 256) w_lds[idx] = W[idx];
    __syncthreads();

    // stage Bs = qu (bf16, 64 x 256), fold s_q partials (shfl-reduced)
    {
      const int bj = tid >> 2, bc = tid & 3;
      const float4* src = (const float4*)(qu + ((size_t)(b * LQQ + bj)) * DDD + bc * 64);
      const float* wq = w_lds + bc * 64;
      unsigned short* dst = Bs + bj * 264 + bc * 64;
      float sqp = 0.f;
#pragma unroll
      for (int u = 0; u < 16; ++u) {
        float4 v = src[u];
        sqp += v.x * wq[u*4+0] + v.y * wq[u*4+1] + v.z * wq[u*4+2] + v.w * wq[u*4+3];
        uint2 o = { pk2bf(v.x, v.y), pk2bf(v.z, v.w) };
        *(uint2*)(dst + u * 4) = o;
      }
      sqp += __shfl_xor(sqp, 1);
      sqp += __shfl_xor(sqp, 2);
      if ((tid & 3) == 0) sq_lds[bj] = sqp;
    }
    __syncthreads();

    f32x4 acc[4];
#pragma unroll
    for (int c = 0; c < 4; ++c) acc[c] = (f32x4){0.f, 0.f, 0.f, 0.f};

    float scp = 0.f;
    const float* cxrow = cx + ((size_t)(b * LCC + i0 + w * 16 + ln)) * DDD;
#pragma unroll
    for (int kk = 0; kk < 4; ++kk)
#pragma unroll
      for (int ks = 0; ks < 2; ++ks) {
        const int k0 = kk * 64 + ks * 32 + quad * 8;
        float4 c0 = *(const float4*)(cxrow + k0);
        float4 c1 = *(const float4*)(cxrow + k0 + 4);
        const float* wcp = w_lds + 256 + k0;
        const float* wip = w_lds + 512 + k0;
        scp += c0.x*wcp[0] + c0.y*wcp[1] + c0.z*wcp[2] + c0.w*wcp[3]
             + c1.x*wcp[4] + c1.y*wcp[5] + c1.z*wcp[6] + c1.w*wcp[7];
        u32x4 av = { pk2bf(c0.x * wip[0], c0.y * wip[1]),
                     pk2bf(c0.z * wip[2], c0.w * wip[3]),
                     pk2bf(c1.x * wip[4], c1.y * wip[5]),
                     pk2bf(c1.z * wip[6], c1.w * wip[7]) };
        bf16x8 af;
        __builtin_memcpy(&af, &av, sizeof(af));
#pragma unroll
        for (int tn = 0; tn < 4; ++tn) {
          bf16x8 bf = *(const bf16x8*)(Bs + (tn * 16 + ln) * 264 + k0);
          acc[tn] = __builtin_amdgcn_mfma_f32_16x16x32_bf16(af, bf, acc[tn], 0, 0, 0);
        }
      }

    scp += __shfl_xor(scp, 16);
    scp += __shfl_xor(scp, 32);
    if (lane < 16) sc_lds[w * 16 + ln] = scp + Wb[0];
    __syncthreads();

#pragma unroll
    for (int tn = 0; tn < 4; ++tn)
#pragma unroll
      for (int r = 0; r < 4; ++r) {
        int il = w * 16 + quad * 4 + r;
        int j  = tn * 16 + ln;
        E_lds[il * 65 + j] = __expf(acc[tn][r] + sc_lds[il] + sq_lds[j]);
      }
    __syncthreads();

    // rowsum -> P = diag(1/rowsum)*E
    {
      const int i = tid >> 2, c = tid & 3;
      const float* srcr = E_lds + i * 65 + c * 16;
      float sum = 0.f;
#pragma unroll
      for (int j = 0; j < 16; ++j) sum += srcr[j];
      sum += __shfl_xor(sum, 1);
      sum += __shfl_xor(sum, 2);
      const float ri = 1.0f / sum;
      unsigned short* dst = P + ((size_t)(b * LCC + i0 + i)) * 64 + c * 16;
#pragma unroll
      for (int u = 0; u < 4; ++u) {
        uint2 o = { pk2bf(srcr[u*4+0]*ri, srcr[u*4+1]*ri),
                    pk2bf(srcr[u*4+2]*ri, srcr[u*4+3]*ri) };
        *(uint2*)(dst + u * 4) = o;
      }
    }
    // colsum partials -> csp
    {
      const int j = tid >> 2, c = tid & 3;
      float sum = 0.f;
#pragma unroll
      for (int r = 0; r < 16; ++r) sum += E_lds[(c * 16 + r) * 65 + j];
      sum += __shfl_xor(sum, 1);
      sum += __shfl_xor(sum, 2);
      if ((tid & 3) == 0) csp[((size_t)(b * 8 + s)) * 64 + j] = sum;
    }
    // E^T (unscaled)
    {
      const int j = tid >> 2, c = tid & 3;
      unsigned short* dst = Et + ((size_t)(b * LQQ + j)) * LCC + i0 + c * 16;
#pragma unroll
      for (int u = 0; u < 4; ++u) {
        uint2 o = { pk2bf(E_lds[(c*16 + u*4 + 0) * 65 + j],
                          E_lds[(c*16 + u*4 + 1) * 65 + j]),
                    pk2bf(E_lds[(c*16 + u*4 + 2) * 65 + j],
                          E_lds[(c*16 + u*4 + 3) * 65 + j]) };
        *(uint2*)(dst + u * 4) = o;
      }
    }
  }

  signal_cnt(&cnt1[b], tid);   // fence + barrier + release (also frees smem)

  // ======================= phase 2: T matrix (d-slice = s) ==================
  {
    unsigned short* Bs2 = (unsigned short*)(smem);          // 2 x 32*72 us
    float* Tl           = (float*)(smem + 9216);            // 64*37 f
    float* csinv        = (float*)(smem + 18688);           // 64 f
    const int d0 = s * 32;

    // Qt transpose staging (independent of phase-1 results) — overlaps the wait
    {
      const int j = tid >> 2, c = tid & 3;
      const float* srow = qu + ((size_t)(b * LQQ + j)) * DDD + d0 + c * 8;
      float4 v0 = *(const float4*)srow;
      float4 v1 = *(const float4*)(srow + 4);
      float* t = Tl + j * 37 + c * 8;
      t[0]=v0.x; t[1]=v0.y; t[2]=v0.z; t[3]=v0.w;
      t[4]=v1.x; t[5]=v1.y; t[6]=v1.z; t[7]=v1.w;
    }
    if (tid == 0) wait_cnt(&cnt1[b], 8);
    __syncthreads();   // Tl ready + phase-1 data acquired

    {
      const int d = tid >> 3, cj = tid & 7;
      unsigned short* dst = Qt + ((size_t)(b * DDD + d0 + d)) * 64 + cj * 8;
      uint2 o0 = { pk2bf(Tl[(cj*8+0)*37+d], Tl[(cj*8+1)*37+d]),
                   pk2bf(Tl[(cj*8+2)*37+d], Tl[(cj*8+3)*37+d]) };
      uint2 o1 = { pk2bf(Tl[(cj*8+4)*37+d], Tl[(cj*8+5)*37+d]),
                   pk2bf(Tl[(cj*8+6)*37+d], Tl[(cj*8+7)*37+d]) };
      *(uint2*)dst = o0;
      *(uint2*)(dst + 4) = o1;
    }
    if (tid < 64) {
      float sum = 0.f;
#pragma unroll
      for (int t = 0; t < 8; ++t) sum += csp[((size_t)(b * 8 + t)) * 64 + tid];
      csinv[tid] = 1.0f / sum;
    }

    f32x4 acc[2];
    acc[0] = (f32x4){0.f, 0.f, 0.f, 0.f};
    acc[1] = (f32x4){0.f, 0.f, 0.f, 0.f};
    const unsigned short* etrow = Et + ((size_t)(b * LQQ + w * 16 + ln)) * LCC;
    const int r2 = tid >> 2, c2 = tid & 3;

    for (int kk = 0; kk < 8; ++kk) {
      unsigned short* bufw = Bs2 + (kk & 1) * 2304;
      {
        const float* srow = cx + ((size_t)(b * LCC + kk * 64 + r2)) * DDD + d0 + c2 * 8;
        float4 v0 = *(const float4*)srow;
        float4 v1 = *(const float4*)(srow + 4);
        bufw[(c2*8+0)*72 + r2] = bf1(v0.x);
        bufw[(c2*8+1)*72 + r2] = bf1(v0.y);
        bufw[(c2*8+2)*72 + r2] = bf1(v0.z);
        bufw[(c2*8+3)*72 + r2] = bf1(v0.w);
        bufw[(c2*8+4)*72 + r2] = bf1(v1.x);
        bufw[(c2*8+5)*72 + r2] = bf1(v1.y);
        bufw[(c2*8+6)*72 + r2] = bf1(v1.z);
        bufw[(c2*8+7)*72 + r2] = bf1(v1.w);
      }
      bf16x8 af0 = *(const bf16x8*)(etrow + kk * 64 + quad * 8);
      bf16x8 af1 = *(const bf16x8*)(etrow + kk * 64 + 32 + quad * 8);
      __syncthreads();
      const unsigned short* bufr = Bs2 + (kk & 1) * 2304;
#pragma unroll
      for (int tn = 0; tn < 2; ++tn) {
        bf16x8 bf0  = *(const bf16x8*)(bufr + (tn * 16 + ln) * 72 + quad * 8);
        bf16x8 bf1v = *(const bf16x8*)(bufr + (tn * 16 + ln) * 72 + 32 + quad * 8);
        acc[tn] = __builtin_amdgcn_mfma_f32_16x16x32_bf16(af0, bf0, acc[tn], 0, 0, 0);
        acc[tn] = __builtin_amdgcn_mfma_f32_16x16x32_bf16(af1, bf1v, acc[tn], 0, 0, 0);
      }
    }

#pragma unroll
    for (int tn = 0; tn < 2; ++tn)
#pragma unroll
      for (int r = 0; r < 4; ++r) {
        int j = w * 16 + quad * 4 + r;
        Tl[j * 37 + tn * 16 + ln] = acc[tn][r] * csinv[j];
      }
    __syncthreads();
    {
      const int d = tid >> 3, cj = tid & 7;
      unsigned short* dst = Tt + ((size_t)(b * DDD + d0 + d)) * 64 + cj * 8;
      uint2 o0 = { pk2bf(Tl[(cj*8+0)*37+d], Tl[(cj*8+1)*37+d]),
                   pk2bf(Tl[(cj*8+2)*37+d], Tl[(cj*8+3)*37+d]) };
      uint2 o1 = { pk2bf(Tl[(cj*8+4)*37+d], Tl[(cj*8+5)*37+d]),
                   pk2bf(Tl[(cj*8+6)*37+d], Tl[(cj*8+7)*37+d]) };
      *(uint2*)dst = o0;
      *(uint2*)(dst + 4) = o1;
    }
  }

  signal_cnt(&cnt2[b], tid);
  if (tid == 0) wait_cnt(&cnt2[b], 8);
  __syncthreads();

  // ======================= phase 3: outputs (tile = s) ======================
  {
    float* TrA = (float*)(smem);            // 16*260 f
    float* TrB = (float*)(smem + 16640);    // 16*260 f
    const int i0 = s * 64;

    const unsigned short* pbase = P + ((size_t)(b * LCC + i0)) * 64;
    const unsigned short* qbase = Qt + (size_t)b * DDD * 64;
    const unsigned short* tbase = Tt + (size_t)b * DDD * 64;

    f32x4 accA[4][4], accB[4][4];
#pragma unroll
    for (int a = 0; a < 4; ++a)
#pragma unroll
      for (int c = 0; c < 4; ++c) {
        accA[a][c] = (f32x4){0.f, 0.f, 0.f, 0.f};
        accB[a][c] = (f32x4){0.f, 0.f, 0.f, 0.f};
      }

#pragma unroll
    for (int ks = 0; ks < 2; ++ks) {
      bf16x8 af[4];
#pragma unroll
      for (int tm = 0; tm < 4; ++tm)
        af[tm] = *(const bf16x8*)(pbase + (tm * 16 + ln) * 64 + ks * 32 + quad * 8);
#pragma unroll
      for (int tn = 0; tn < 4; ++tn) {
        const size_t boff = ((size_t)(w * 64 + tn * 16 + ln)) * 64 + ks * 32 + quad * 8;
        bf16x8 bq = *(const bf16x8*)(qbase + boff);
        bf16x8 bt = *(const bf16x8*)(tbase + boff);
#pragma unroll
        for (int tm = 0; tm < 4; ++tm) {
          accA[tm][tn] = __builtin_amdgcn_mfma_f32_16x16x32_bf16(af[tm], bq, accA[tm][tn], 0, 0, 0);
          accB[tm][tn] = __builtin_amdgcn_mfma_f32_16x16x32_bf16(af[tm], bt, accB[tm][tn], 0, 0, 0);
        }
      }
    }

    const float* cxb = cx + (size_t)b * LCC * DDD;
    float* ob = out + (size_t)b * LCC * 1024;
    const int row = tid >> 4;
    const int fq  = tid & 15;

#pragma unroll
    for (int tm = 0; tm < 4; ++tm) {
#pragma unroll
      for (int tn = 0; tn < 4; ++tn)
#pragma unroll
        for (int r = 0; r < 4; ++r) {
          int rloc = quad * 4 + r;
          TrA[rloc * 260 + w * 64 + tn * 16 + ln] = accA[tm][tn][r];
          TrB[rloc * 260 + w * 64 + tn * 16 + ln] = accB[tm][tn][r];
        }
      __syncthreads();
      const int i = i0 + tm * 16 + row;
#pragma unroll
      for (int u = 0; u < 4; ++u) {
        int c0 = (fq + u * 16) * 4;
        float4 a  = *(const float4*)(TrA + row * 260 + c0);
        float4 bm = *(const float4*)(TrB + row * 260 + c0);
        float4 c  = *(const float4*)(cxb + (size_t)i * DDD + c0);
        nt_store4(ob + (size_t)i * 1024 + c0,       c.x, c.y, c.z, c.w);
        nt_store4(ob + (size_t)i * 1024 + 256 + c0, a.x, a.y, a.z, a.w);
        nt_store4(ob + (size_t)i * 1024 + 512 + c0, c.x*a.x, c.y*a.y, c.z*a.z, c.w*a.w);
        nt_store4(ob + (size_t)i * 1024 + 768 + c0, c.x*bm.x, c.y*bm.y, c.z*bm.z, c.w*bm.w);
      }
      __syncthreads();
    }
  }
}

extern "C" void kernel_launch(void* const* d_in, const int* in_sizes, int n_in,
                              void* d_out, int out_size, void* d_ws, size_t ws_size,
                              hipStream_t stream) {
  const float* cx = (const float*)d_in[0];
  const float* qu = (const float*)d_in[1];
  const float* W  = (const float*)d_in[2];
  const float* Wb = (const float*)d_in[3];
  float* out = (float*)d_out;

  char* wsb = (char*)d_ws;
  unsigned short* P   = (unsigned short*)(wsb);                       // 4 MiB
  unsigned short* Et  = (unsigned short*)(wsb + (4ull << 20));        // 4 MiB
  unsigned short* Qt  = (unsigned short*)(wsb + (8ull << 20));        // 2 MiB
  unsigned short* Tt  = (unsigned short*)(wsb + (10ull << 20));       // 2 MiB
  float*          csp = (float*)(wsb + (12ull << 20));                // 128 KiB
  int*            cnt = (int*)(wsb + (13ull << 20));                  // 512 B

  hipMemsetAsync(cnt, 0, 512, stream);
  fused<<<dim3(512), dim3(256), 0, stream>>>(cx, qu, W, Wb, P, Et, csp, Qt, Tt,
                                             out, cnt, cnt + 64);
}

// Round 6
// 210.899 us; speedup vs baseline: 1.9070x; 1.9070x over previous
//
#include <hip/hip_runtime.h>
#include <hip/hip_bf16.h>

#define BB 64
#define LCC 512
#define LQQ 64
#define DDD 256

typedef short bf16x8 __attribute__((ext_vector_type(8)));
typedef float f32x4 __attribute__((ext_vector_type(4)));
typedef unsigned u32x4 __attribute__((ext_vector_type(4)));

// HW packed conversion: 2 floats -> 2 bf16 in one v_cvt_pk_bf16_f32 (gfx950).
static __device__ __forceinline__ unsigned pk2bf(float a, float b) {
  __hip_bfloat162 h = __float22bfloat162_rn(make_float2(a, b));
  unsigned u;
  __builtin_memcpy(&u, &h, sizeof(u));
  return u;
}
static __device__ __forceinline__ unsigned short bf1(float f) {
  __hip_bfloat16 h = __float2bfloat16(f);
  unsigned short u;
  __builtin_memcpy(&u, &h, sizeof(u));
  return u;
}

static __device__ __forceinline__ void nt_store4(float* p, float a, float b, float c, float d) {
  f32x4 v = { a, b, c, d };
  __builtin_nontemporal_store(v, (f32x4*)p);
}

// ---------------------------------------------------------------------------
// Kernel 1: E = exp((cx*wi)@qu^T + s_c + s_q + bias); writes
//   P  = diag(1/rowsum) * E   (bf16)
//   Et = E^T                  (bf16, unscaled)
//   csp[b][tile][64]          (f32 per-tile column-sum partials)
// 32-row tiles: grid 1024 = B x 16; 4 waves split rows(rh) x cols(ch).
// LDS ~45 KB -> 3 blocks/CU (was 2).
// ---------------------------------------------------------------------------
__global__ __launch_bounds__(256) void k1_scores(
    const float* __restrict__ cx, const float* __restrict__ qu,
    const float* __restrict__ W, const float* __restrict__ Wb,
    unsigned short* __restrict__ P, unsigned short* __restrict__ Et,
    float* __restrict__ csp)
{
  __shared__ float w_lds[768];                 // wq | wc | wi
  __shared__ unsigned short Bs[64 * 264];      // qu tile bf16, full K, +8 pad
  __shared__ float E_lds[32 * 65];
  __shared__ float sc_lds[32];
  __shared__ float sq_lds[64];

  const int tid = threadIdx.x;
  const int b  = blockIdx.x >> 4;
  const int ts = blockIdx.x & 15;
  const int i0 = ts * 32;
  const int w = tid >> 6, lane = tid & 63, quad = lane >> 4, ln = lane & 15;
  const int rh = w & 1, ch = w >> 1;   // row-half, col-half

  for (int idx = tid; idx < 768; idx += 256) w_lds[idx] = W[idx];
  __syncthreads();

  // stage Bs = qu (bf16, 64 x 256), fold s_q partials (shfl-reduced)
  {
    const int bj = tid >> 2, bc = tid & 3;
    const float4* src = (const float4*)(qu + ((size_t)(b * LQQ + bj)) * DDD + bc * 64);
    const float* wq = w_lds + bc * 64;
    unsigned short* dst = Bs + bj * 264 + bc * 64;
    float sqp = 0.f;
#pragma unroll
    for (int u = 0; u < 16; ++u) {
      float4 v = src[u];
      sqp += v.x * wq[u*4+0] + v.y * wq[u*4+1] + v.z * wq[u*4+2] + v.w * wq[u*4+3];
      uint2 o = { pk2bf(v.x, v.y), pk2bf(v.z, v.w) };
      *(uint2*)(dst + u * 4) = o;
    }
    sqp += __shfl_xor(sqp, 1);
    sqp += __shfl_xor(sqp, 2);
    if ((tid & 3) == 0) sq_lds[bj] = sqp;
  }
  __syncthreads();

  f32x4 acc[2];
  acc[0] = (f32x4){0.f, 0.f, 0.f, 0.f};
  acc[1] = (f32x4){0.f, 0.f, 0.f, 0.f};

  // K loop: no barriers. A fragment = cx row (rh*16+ln), k-slice quad*8.
  float scp = 0.f;
  const float* cxrow = cx + ((size_t)(b * LCC + i0 + rh * 16 + ln)) * DDD;
#pragma unroll
  for (int kk = 0; kk < 4; ++kk)
#pragma unroll
    for (int ks = 0; ks < 2; ++ks) {
      const int k0 = kk * 64 + ks * 32 + quad * 8;
      float4 c0 = *(const float4*)(cxrow + k0);
      float4 c1 = *(const float4*)(cxrow + k0 + 4);
      const float* wcp = w_lds + 256 + k0;
      const float* wip = w_lds + 512 + k0;
      scp += c0.x*wcp[0] + c0.y*wcp[1] + c0.z*wcp[2] + c0.w*wcp[3]
           + c1.x*wcp[4] + c1.y*wcp[5] + c1.z*wcp[6] + c1.w*wcp[7];
      u32x4 av = { pk2bf(c0.x * wip[0], c0.y * wip[1]),
                   pk2bf(c0.z * wip[2], c0.w * wip[3]),
                   pk2bf(c1.x * wip[4], c1.y * wip[5]),
                   pk2bf(c1.z * wip[6], c1.w * wip[7]) };
      bf16x8 af;
      __builtin_memcpy(&af, &av, sizeof(af));
#pragma unroll
      for (int tn = 0; tn < 2; ++tn) {
        bf16x8 bf = *(const bf16x8*)(Bs + ((ch * 2 + tn) * 16 + ln) * 264 + k0);
        acc[tn] = __builtin_amdgcn_mfma_f32_16x16x32_bf16(af, bf, acc[tn], 0, 0, 0);
      }
    }

  // reduce s_c across quads (shfl butterfly over lane bits 4,5), add bias.
  // ch=0 waves (w=0,1) cover both row halves.
  scp += __shfl_xor(scp, 16);
  scp += __shfl_xor(scp, 32);
  if (w < 2 && lane < 16) sc_lds[w * 16 + ln] = scp + Wb[0];
  __syncthreads();

  // exp epilogue into E_lds (C/D layout: col=lane&15, row=quad*4+r)
#pragma unroll
  for (int tn = 0; tn < 2; ++tn)
#pragma unroll
    for (int r = 0; r < 4; ++r) {
      int il = rh * 16 + quad * 4 + r;
      int j  = (ch * 2 + tn) * 16 + ln;
      E_lds[il * 65 + j] = __expf(acc[tn][r] + sc_lds[il] + sq_lds[j]);
    }
  __syncthreads();

  // rowsum (8 threads/row, shfl-combined) -> P = diag(1/rowsum)*E
  {
    const int i = tid >> 3, c = tid & 7;
    const float* srcr = E_lds + i * 65 + c * 8;
    float s = 0.f;
#pragma unroll
    for (int j = 0; j < 8; ++j) s += srcr[j];
    s += __shfl_xor(s, 1);
    s += __shfl_xor(s, 2);
    s += __shfl_xor(s, 4);
    const float ri = 1.0f / s;
    u32x4 o = { pk2bf(srcr[0]*ri, srcr[1]*ri), pk2bf(srcr[2]*ri, srcr[3]*ri),
                pk2bf(srcr[4]*ri, srcr[5]*ri), pk2bf(srcr[6]*ri, srcr[7]*ri) };
    *(u32x4*)(P + ((size_t)(b * LCC + i0 + i)) * 64 + c * 8) = o;
  }
  // colsum partials (f32, unscaled E) -> csp (shfl-combined)
  {
    const int j = tid >> 2, c = tid & 3;
    float s = 0.f;
#pragma unroll
    for (int u = 0; u < 8; ++u) s += E_lds[(c * 8 + u) * 65 + j];
    s += __shfl_xor(s, 1);
    s += __shfl_xor(s, 2);
    if ((tid & 3) == 0) csp[((size_t)(b * 16 + ts)) * 64 + j] = s;
  }
  // write E^T (B, 64, 512) bf16 (unscaled — k2 applies colsum scaling)
  {
    const int j = tid >> 2, c = tid & 3;
    u32x4 o = { pk2bf(E_lds[(c*8+0)*65 + j], E_lds[(c*8+1)*65 + j]),
                pk2bf(E_lds[(c*8+2)*65 + j], E_lds[(c*8+3)*65 + j]),
                pk2bf(E_lds[(c*8+4)*65 + j], E_lds[(c*8+5)*65 + j]),
                pk2bf(E_lds[(c*8+6)*65 + j], E_lds[(c*8+7)*65 + j]) };
    *(u32x4*)(Et + ((size_t)(b * LQQ + j)) * LCC + i0 + c * 8) = o;
  }
}

// ---------------------------------------------------------------------------
// Kernel 2: T = diag(1/colsum) * E^T @ contex -> T^T (bf16); also Q^T (bf16)
// 16-wide D-slices: grid 1024 = B x 16; acc[1]; double-buffered staging.
// LDS ~10 KB -> 4 blocks/CU (was 2).
// ---------------------------------------------------------------------------
__global__ __launch_bounds__(256) void k2_tmat(
    const float* __restrict__ cx, const float* __restrict__ qu,
    const unsigned short* __restrict__ Et, const float* __restrict__ csp,
    unsigned short* __restrict__ Qt, unsigned short* __restrict__ Tt)
{
  __shared__ unsigned short Bs2[2][16 * 72];
  __shared__ float Tl[64 * 20];
  __shared__ float csinv[64];

  const int tid = threadIdx.x;
  const int b  = blockIdx.x >> 4;
  const int d0 = (blockIdx.x & 15) * 16;
  const int w = tid >> 6, lane = tid & 63, quad = lane >> 4, ln = lane & 15;

  // ---- transpose question slice -> Qt ----
  {
    const int j = tid >> 2, c = tid & 3;
    float4 v = *(const float4*)(qu + ((size_t)(b * LQQ + j)) * DDD + d0 + c * 4);
    float* t = Tl + j * 20 + c * 4;
    t[0] = v.x; t[1] = v.y; t[2] = v.z; t[3] = v.w;
  }
  // exact colsum inverse from k1's f32 partials (16 tiles now)
  if (tid < 64) {
    float s = 0.f;
#pragma unroll
    for (int t = 0; t < 16; ++t) s += csp[((size_t)(b * 16 + t)) * 64 + tid];
    csinv[tid] = 1.0f / s;
  }
  __syncthreads();
  {
    const int d = tid >> 4, cj = tid & 15;
    unsigned short* dst = Qt + ((size_t)(b * DDD + d0 + d)) * 64 + cj * 4;
    uint2 o = { pk2bf(Tl[(cj*4+0)*20 + d], Tl[(cj*4+1)*20 + d]),
                pk2bf(Tl[(cj*4+2)*20 + d], Tl[(cj*4+3)*20 + d]) };
    *(uint2*)dst = o;
  }

  f32x4 acc = (f32x4){0.f, 0.f, 0.f, 0.f};
  const unsigned short* etrow = Et + ((size_t)(b * LQQ + w * 16 + ln)) * LCC;
  const int r2 = tid >> 2, c2 = tid & 3;

  for (int kk = 0; kk < 8; ++kk) {
    unsigned short* bufw = Bs2[kk & 1];
    // stage Bs2[d][i] = contex[k0+i][d0+d] (bf16 transposed)
    {
      const float* srow = cx + ((size_t)(b * LCC + kk * 64 + r2)) * DDD + d0 + c2 * 4;
      float4 v = *(const float4*)srow;
      bufw[(c2*4+0)*72 + r2] = bf1(v.x);
      bufw[(c2*4+1)*72 + r2] = bf1(v.y);
      bufw[(c2*4+2)*72 + r2] = bf1(v.z);
      bufw[(c2*4+3)*72 + r2] = bf1(v.w);
    }
    // direct-global A fragments
    bf16x8 af0 = *(const bf16x8*)(etrow + kk * 64 + quad * 8);
    bf16x8 af1 = *(const bf16x8*)(etrow + kk * 64 + 32 + quad * 8);
    __syncthreads();
    const unsigned short* bufr = Bs2[kk & 1];
    bf16x8 bf0  = *(const bf16x8*)(bufr + ln * 72 + quad * 8);
    bf16x8 bf1v = *(const bf16x8*)(bufr + ln * 72 + 32 + quad * 8);
    acc = __builtin_amdgcn_mfma_f32_16x16x32_bf16(af0, bf0, acc, 0, 0, 0);
    acc = __builtin_amdgcn_mfma_f32_16x16x32_bf16(af1, bf1v, acc, 0, 0, 0);
  }

  // park T (scaled) into Tl
#pragma unroll
  for (int r = 0; r < 4; ++r) {
    int j = w * 16 + quad * 4 + r;
    Tl[j * 20 + ln] = acc[r] * csinv[j];
  }
  __syncthreads();
  // write T^T (B, 256, 64) bf16
  {
    const int d = tid >> 4, cj = tid & 15;
    unsigned short* dst = Tt + ((size_t)(b * DDD + d0 + d)) * 64 + cj * 4;
    uint2 o = { pk2bf(Tl[(cj*4+0)*20 + d], Tl[(cj*4+1)*20 + d]),
                pk2bf(Tl[(cj*4+2)*20 + d], Tl[(cj*4+3)*20 + d]) };
    *(uint2*)dst = o;
  }
}

// ---------------------------------------------------------------------------
// Kernel 3: A = P @ qu, Bm = P @ T  (P already rowsum-scaled). 32-row tiles:
// grid 1024 = B x 16; acc halved -> ~75 VGPR; LDS 33 KB -> 4 blocks/CU.
// Writes all four output chunks [cx | A | cx*A | cx*Bm] fully coalesced.
// ---------------------------------------------------------------------------
__global__ __launch_bounds__(256) void k3_out(
    const float* __restrict__ cx,
    const unsigned short* __restrict__ P,
    const unsigned short* __restrict__ Qt,
    const unsigned short* __restrict__ Tt,
    float* __restrict__ out)
{
  __shared__ float TrA[16 * 260];
  __shared__ float TrB[16 * 260];

  const int tid = threadIdx.x;
  const int b  = blockIdx.x >> 4;
  const int i0 = (blockIdx.x & 15) * 32;
  const int w = tid >> 6, lane = tid & 63, quad = lane >> 4, ln = lane & 15;

  const unsigned short* pbase = P + ((size_t)(b * LCC + i0)) * 64;
  const unsigned short* qbase = Qt + (size_t)b * DDD * 64;
  const unsigned short* tbase = Tt + (size_t)b * DDD * 64;

  f32x4 accA[2][4], accB[2][4];
#pragma unroll
  for (int a = 0; a < 2; ++a)
#pragma unroll
    for (int c = 0; c < 4; ++c) {
      accA[a][c] = (f32x4){0.f, 0.f, 0.f, 0.f};
      accB[a][c] = (f32x4){0.f, 0.f, 0.f, 0.f};
    }

#pragma unroll
  for (int ks = 0; ks < 2; ++ks) {
    bf16x8 af[2];
#pragma unroll
    for (int tm = 0; tm < 2; ++tm)
      af[tm] = *(const bf16x8*)(pbase + (tm * 16 + ln) * 64 + ks * 32 + quad * 8);
#pragma unroll
    for (int tn = 0; tn < 4; ++tn) {
      const size_t boff = ((size_t)(w * 64 + tn * 16 + ln)) * 64 + ks * 32 + quad * 8;
      bf16x8 bq = *(const bf16x8*)(qbase + boff);
      bf16x8 bt = *(const bf16x8*)(tbase + boff);
#pragma unroll
      for (int tm = 0; tm < 2; ++tm) {
        accA[tm][tn] = __builtin_amdgcn_mfma_f32_16x16x32_bf16(af[tm], bq, accA[tm][tn], 0, 0, 0);
        accB[tm][tn] = __builtin_amdgcn_mfma_f32_16x16x32_bf16(af[tm], bt, accB[tm][tn], 0, 0, 0);
      }
    }
  }

  const float* cxb = cx + (size_t)b * LCC * DDD;
  float* ob = out + (size_t)b * LCC * 1024;
  const int row = tid >> 4;   // 0..15
  const int fq  = tid & 15;

#pragma unroll
  for (int tm = 0; tm < 2; ++tm) {
    // park 16 rows x 256 cols of A and Bm (C/D-layout -> row-major)
#pragma unroll
    for (int tn = 0; tn < 4; ++tn)
#pragma unroll
      for (int r = 0; r < 4; ++r) {
        int rloc = quad * 4 + r;
        TrA[rloc * 260 + w * 64 + tn * 16 + ln] = accA[tm][tn][r];
        TrB[rloc * 260 + w * 64 + tn * 16 + ln] = accB[tm][tn][r];
      }
    __syncthreads();
    const int i = i0 + tm * 16 + row;
#pragma unroll
    for (int u = 0; u < 4; ++u) {
      int c0 = (fq + u * 16) * 4;
      float4 a  = *(const float4*)(TrA + row * 260 + c0);
      float4 bm = *(const float4*)(TrB + row * 260 + c0);
      float4 c  = *(const float4*)(cxb + (size_t)i * DDD + c0);
      nt_store4(ob + (size_t)i * 1024 + c0,       c.x, c.y, c.z, c.w);
      nt_store4(ob + (size_t)i * 1024 + 256 + c0, a.x, a.y, a.z, a.w);
      nt_store4(ob + (size_t)i * 1024 + 512 + c0, c.x*a.x, c.y*a.y, c.z*a.z, c.w*a.w);
      nt_store4(ob + (size_t)i * 1024 + 768 + c0, c.x*bm.x, c.y*bm.y, c.z*bm.z, c.w*bm.w);
    }
    __syncthreads();   // reads done before next park
  }
}

extern "C" void kernel_launch(void* const* d_in, const int* in_sizes, int n_in,
                              void* d_out, int out_size, void* d_ws, size_t ws_size,
                              hipStream_t stream) {
  const float* cx = (const float*)d_in[0];
  const float* qu = (const float*)d_in[1];
  const float* W  = (const float*)d_in[2];
  const float* Wb = (const float*)d_in[3];
  float* out = (float*)d_out;

  char* wsb = (char*)d_ws;
  unsigned short* P   = (unsigned short*)(wsb);                       // 4 MiB
  unsigned short* Et  = (unsigned short*)(wsb + (4ull << 20));        // 4 MiB
  unsigned short* Qt  = (unsigned short*)(wsb + (8ull << 20));        // 2 MiB
  unsigned short* Tt  = (unsigned short*)(wsb + (10ull << 20));       // 2 MiB
  float*          csp = (float*)(wsb + (12ull << 20));                // 256 KiB

  k1_scores<<<dim3(1024), dim3(256), 0, stream>>>(cx, qu, W, Wb, P, Et, csp);
  k2_tmat  <<<dim3(1024), dim3(256), 0, stream>>>(cx, qu, Et, csp, Qt, Tt);
  k3_out   <<<dim3(1024), dim3(256), 0, stream>>>(cx, P, Qt, Tt, out);
}

// Round 7
// 199.203 us; speedup vs baseline: 2.0190x; 1.0587x over previous
//
#include <hip/hip_runtime.h>
#include <hip/hip_bf16.h>

#define BB 64
#define LCC 512
#define LQQ 64
#define DDD 256

typedef short bf16x8 __attribute__((ext_vector_type(8)));
typedef float f32x4 __attribute__((ext_vector_type(4)));
typedef unsigned u32x4 __attribute__((ext_vector_type(4)));

// HW packed conversion: 2 floats -> 2 bf16 in one v_cvt_pk_bf16_f32 (gfx950).
static __device__ __forceinline__ unsigned pk2bf(float a, float b) {
  __hip_bfloat162 h = __float22bfloat162_rn(make_float2(a, b));
  unsigned u;
  __builtin_memcpy(&u, &h, sizeof(u));
  return u;
}
static __device__ __forceinline__ unsigned short bf1(float f) {
  __hip_bfloat16 h = __float2bfloat16(f);
  unsigned short u;
  __builtin_memcpy(&u, &h, sizeof(u));
  return u;
}

static __device__ __forceinline__ void nt_store4(float* p, float a, float b, float c, float d) {
  f32x4 v = { a, b, c, d };
  __builtin_nontemporal_store(v, (f32x4*)p);
}

// ---------------------------------------------------------------------------
// Kernel 1: E = exp((cx*wi)@qu^T + s_c + s_q + bias); writes
//   P  = diag(1/rowsum) * E   (bf16)
//   Et = E^T                  (bf16, unscaled)
//   csp[b][tile][64]          (f32 per-tile column-sum partials)
// HW cvt_pk for all f32->bf16; shuffle reductions (no red[] LDS, 4 barriers).
// grid 512 = B x 8 LC-tiles of 64; 256 threads (4 waves).
// ---------------------------------------------------------------------------
__global__ __launch_bounds__(256) void k1_scores(
    const float* __restrict__ cx, const float* __restrict__ qu,
    const float* __restrict__ W, const float* __restrict__ Wb,
    unsigned short* __restrict__ P, unsigned short* __restrict__ Et,
    float* __restrict__ csp)
{
  __shared__ float w_lds[768];                 // wq | wc | wi
  __shared__ unsigned short Bs[64 * 264];      // qu tile bf16, full K, +8 pad
  __shared__ float E_lds[64 * 65];
  __shared__ float sc_lds[64];
  __shared__ float sq_lds[64];

  const int tid = threadIdx.x;
  const int b    = blockIdx.x >> 3;
  const int tile = blockIdx.x & 7;
  const int i0 = tile * 64;
  const int w = tid >> 6, lane = tid & 63, quad = lane >> 4, ln = lane & 15;

  for (int idx = tid; idx < 768; idx += 256) w_lds[idx] = W[idx];
  __syncthreads();

  // stage Bs = qu (bf16, 64 x 256), fold s_q partials (shfl-reduced)
  {
    const int bj = tid >> 2, bc = tid & 3;
    const float4* src = (const float4*)(qu + ((size_t)(b * LQQ + bj)) * DDD + bc * 64);
    const float* wq = w_lds + bc * 64;
    unsigned short* dst = Bs + bj * 264 + bc * 64;
    float sqp = 0.f;
#pragma unroll
    for (int u = 0; u < 16; ++u) {
      float4 v = src[u];
      sqp += v.x * wq[u*4+0] + v.y * wq[u*4+1] + v.z * wq[u*4+2] + v.w * wq[u*4+3];
      uint2 o = { pk2bf(v.x, v.y), pk2bf(v.z, v.w) };
      *(uint2*)(dst + u * 4) = o;
    }
    sqp += __shfl_xor(sqp, 1);
    sqp += __shfl_xor(sqp, 2);
    if ((tid & 3) == 0) sq_lds[bj] = sqp;
  }
  __syncthreads();

  f32x4 acc[4];
#pragma unroll
  for (int c = 0; c < 4; ++c) acc[c] = (f32x4){0.f, 0.f, 0.f, 0.f};

  // K loop: no barriers. A fragment = cx row (w*16+ln), k-slice quad*8.
  float scp = 0.f;
  const float* cxrow = cx + ((size_t)(b * LCC + i0 + w * 16 + ln)) * DDD;
#pragma unroll
  for (int kk = 0; kk < 4; ++kk)
#pragma unroll
    for (int ks = 0; ks < 2; ++ks) {
      const int k0 = kk * 64 + ks * 32 + quad * 8;
      float4 c0 = *(const float4*)(cxrow + k0);
      float4 c1 = *(const float4*)(cxrow + k0 + 4);
      const float* wcp = w_lds + 256 + k0;
      const float* wip = w_lds + 512 + k0;
      scp += c0.x*wcp[0] + c0.y*wcp[1] + c0.z*wcp[2] + c0.w*wcp[3]
           + c1.x*wcp[4] + c1.y*wcp[5] + c1.z*wcp[6] + c1.w*wcp[7];
      u32x4 av = { pk2bf(c0.x * wip[0], c0.y * wip[1]),
                   pk2bf(c0.z * wip[2], c0.w * wip[3]),
                   pk2bf(c1.x * wip[4], c1.y * wip[5]),
                   pk2bf(c1.z * wip[6], c1.w * wip[7]) };
      bf16x8 af;
      __builtin_memcpy(&af, &av, sizeof(af));
#pragma unroll
      for (int tn = 0; tn < 4; ++tn) {
        bf16x8 bf = *(const bf16x8*)(Bs + (tn * 16 + ln) * 264 + k0);
        acc[tn] = __builtin_amdgcn_mfma_f32_16x16x32_bf16(af, bf, acc[tn], 0, 0, 0);
      }
    }

  // reduce s_c across quads (shfl butterfly over lane bits 4,5), add bias
  scp += __shfl_xor(scp, 16);
  scp += __shfl_xor(scp, 32);
  if (lane < 16) sc_lds[w * 16 + ln] = scp + Wb[0];
  __syncthreads();

  // exp epilogue into E_lds (C/D layout: col=lane&15, row=quad*4+r)
#pragma unroll
  for (int tn = 0; tn < 4; ++tn)
#pragma unroll
    for (int r = 0; r < 4; ++r) {
      int il = w * 16 + quad * 4 + r;
      int j  = tn * 16 + ln;
      E_lds[il * 65 + j] = __expf(acc[tn][r] + sc_lds[il] + sq_lds[j]);
    }
  __syncthreads();

  // rowsum (4 threads/row, shfl-combined) -> P = diag(1/rowsum)*E directly
  {
    const int i = tid >> 2, c = tid & 3;
    const float* srcr = E_lds + i * 65 + c * 16;
    float s = 0.f;
#pragma unroll
    for (int j = 0; j < 16; ++j) s += srcr[j];
    s += __shfl_xor(s, 1);
    s += __shfl_xor(s, 2);
    const float ri = 1.0f / s;
    unsigned short* dst = P + ((size_t)(b * LCC + i0 + i)) * 64 + c * 16;
#pragma unroll
    for (int u = 0; u < 4; ++u) {
      uint2 o = { pk2bf(srcr[u*4+0]*ri, srcr[u*4+1]*ri),
                  pk2bf(srcr[u*4+2]*ri, srcr[u*4+3]*ri) };
      *(uint2*)(dst + u * 4) = o;
    }
  }
  // colsum partials (f32, unscaled E) -> csp (shfl-combined)
  {
    const int j = tid >> 2, c = tid & 3;
    float s = 0.f;
#pragma unroll
    for (int r = 0; r < 16; ++r) s += E_lds[(c * 16 + r) * 65 + j];
    s += __shfl_xor(s, 1);
    s += __shfl_xor(s, 2);
    if ((tid & 3) == 0) csp[((size_t)(b * 8 + tile)) * 64 + j] = s;
  }
  // write E^T (B, 64, 512) bf16 (unscaled — k2 applies colsum scaling)
  {
    const int j = tid >> 2, c = tid & 3;
    unsigned short* dst = Et + ((size_t)(b * LQQ + j)) * LCC + i0 + c * 16;
#pragma unroll
    for (int u = 0; u < 4; ++u) {
      uint2 o = { pk2bf(E_lds[(c*16 + u*4 + 0) * 65 + j],
                        E_lds[(c*16 + u*4 + 1) * 65 + j]),
                  pk2bf(E_lds[(c*16 + u*4 + 2) * 65 + j],
                        E_lds[(c*16 + u*4 + 3) * 65 + j]) };
      *(uint2*)(dst + u * 4) = o;
    }
  }
}

// ---------------------------------------------------------------------------
// Kernel 2: T = diag(1/colsum) * E^T @ contex -> T^T (bf16); also Q^T (bf16)
// Double-buffered staging (1 barrier/iter); HW cvt for bf16 packing.
// grid 512 = B x 8 D-slices of 32; 256 threads (4 waves).
// ---------------------------------------------------------------------------
__global__ __launch_bounds__(256) void k2_tmat(
    const float* __restrict__ cx, const float* __restrict__ qu,
    const unsigned short* __restrict__ Et, const float* __restrict__ csp,
    unsigned short* __restrict__ Qt, unsigned short* __restrict__ Tt)
{
  __shared__ unsigned short Bs2[2][32 * 72];
  __shared__ float Tl[64 * 37];
  __shared__ float csinv[64];

  const int tid = threadIdx.x;
  const int b  = blockIdx.x >> 3;
  const int d0 = (blockIdx.x & 7) * 32;
  const int w = tid >> 6, lane = tid & 63, quad = lane >> 4, ln = lane & 15;

  // ---- transpose question slice -> Qt ----
  {
    const int j = tid >> 2, c = tid & 3;
    const float* srow = qu + ((size_t)(b * LQQ + j)) * DDD + d0 + c * 8;
    float4 v0 = *(const float4*)srow;
    float4 v1 = *(const float4*)(srow + 4);
    float* t = Tl + j * 37 + c * 8;
    t[0]=v0.x; t[1]=v0.y; t[2]=v0.z; t[3]=v0.w;
    t[4]=v1.x; t[5]=v1.y; t[6]=v1.z; t[7]=v1.w;
  }
  // exact colsum inverse from k1's f32 partials
  if (tid < 64) {
    float s = 0.f;
#pragma unroll
    for (int t = 0; t < 8; ++t) s += csp[((size_t)(b * 8 + t)) * 64 + tid];
    csinv[tid] = 1.0f / s;
  }
  __syncthreads();
  {
    const int d = tid >> 3, cj = tid & 7;
    unsigned short* dst = Qt + ((size_t)(b * DDD + d0 + d)) * 64 + cj * 8;
    uint2 o0 = { pk2bf(Tl[(cj*8+0)*37+d], Tl[(cj*8+1)*37+d]),
                 pk2bf(Tl[(cj*8+2)*37+d], Tl[(cj*8+3)*37+d]) };
    uint2 o1 = { pk2bf(Tl[(cj*8+4)*37+d], Tl[(cj*8+5)*37+d]),
                 pk2bf(Tl[(cj*8+6)*37+d], Tl[(cj*8+7)*37+d]) };
    *(uint2*)dst = o0;
    *(uint2*)(dst + 4) = o1;
  }

  f32x4 acc[2];
  acc[0] = (f32x4){0.f, 0.f, 0.f, 0.f};
  acc[1] = (f32x4){0.f, 0.f, 0.f, 0.f};
  const unsigned short* etrow = Et + ((size_t)(b * LQQ + w * 16 + ln)) * LCC;
  const int r2 = tid >> 2, c2 = tid & 3;

  for (int kk = 0; kk < 8; ++kk) {
    unsigned short* bufw = Bs2[kk & 1];
    // stage Bs2[d][i] = contex[k0+i][d0+d] (bf16 transposed)
    // thread owns row r2, 8-col chunk c2 -> 128B contiguous loads per row
    {
      const float* srow = cx + ((size_t)(b * LCC + kk * 64 + r2)) * DDD + d0 + c2 * 8;
      float4 v0 = *(const float4*)srow;
      float4 v1 = *(const float4*)(srow + 4);
      bufw[(c2*8+0)*72 + r2] = bf1(v0.x);
      bufw[(c2*8+1)*72 + r2] = bf1(v0.y);
      bufw[(c2*8+2)*72 + r2] = bf1(v0.z);
      bufw[(c2*8+3)*72 + r2] = bf1(v0.w);
      bufw[(c2*8+4)*72 + r2] = bf1(v1.x);
      bufw[(c2*8+5)*72 + r2] = bf1(v1.y);
      bufw[(c2*8+6)*72 + r2] = bf1(v1.z);
      bufw[(c2*8+7)*72 + r2] = bf1(v1.w);
    }
    // direct-global A fragments
    bf16x8 af0 = *(const bf16x8*)(etrow + kk * 64 + quad * 8);
    bf16x8 af1 = *(const bf16x8*)(etrow + kk * 64 + 32 + quad * 8);
    __syncthreads();
    const unsigned short* bufr = Bs2[kk & 1];
#pragma unroll
    for (int tn = 0; tn < 2; ++tn) {
      bf16x8 bf0 = *(const bf16x8*)(bufr + (tn * 16 + ln) * 72 + quad * 8);
      bf16x8 bf1v = *(const bf16x8*)(bufr + (tn * 16 + ln) * 72 + 32 + quad * 8);
      acc[tn] = __builtin_amdgcn_mfma_f32_16x16x32_bf16(af0, bf0, acc[tn], 0, 0, 0);
      acc[tn] = __builtin_amdgcn_mfma_f32_16x16x32_bf16(af1, bf1v, acc[tn], 0, 0, 0);
    }
  }

  // park T (scaled) into Tl
#pragma unroll
  for (int tn = 0; tn < 2; ++tn)
#pragma unroll
    for (int r = 0; r < 4; ++r) {
      int j = w * 16 + quad * 4 + r;
      Tl[j * 37 + tn * 16 + ln] = acc[tn][r] * csinv[j];
    }
  __syncthreads();
  // write T^T (B, 256, 64) bf16
  {
    const int d = tid >> 3, cj = tid & 7;
    unsigned short* dst = Tt + ((size_t)(b * DDD + d0 + d)) * 64 + cj * 8;
    uint2 o0 = { pk2bf(Tl[(cj*8+0)*37+d], Tl[(cj*8+1)*37+d]),
                 pk2bf(Tl[(cj*8+2)*37+d], Tl[(cj*8+3)*37+d]) };
    uint2 o1 = { pk2bf(Tl[(cj*8+4)*37+d], Tl[(cj*8+5)*37+d]),
                 pk2bf(Tl[(cj*8+6)*37+d], Tl[(cj*8+7)*37+d]) };
    *(uint2*)dst = o0;
    *(uint2*)(dst + 4) = o1;
  }
}

// ---------------------------------------------------------------------------
// Kernel 3: A = P @ qu, Bm = P @ T  (P already rowsum-scaled). One block per
// 64-row tile computes BOTH products; reads P and cx once; writes all four
// output chunks [cx | A | cx*A | cx*Bm] fully coalesced. grid 512 = B x 8.
// ---------------------------------------------------------------------------
__global__ __launch_bounds__(256, 2) void k3_out(
    const float* __restrict__ cx,
    const unsigned short* __restrict__ P,
    const unsigned short* __restrict__ Qt,
    const unsigned short* __restrict__ Tt,
    float* __restrict__ out)
{
  __shared__ float TrA[16 * 260];
  __shared__ float TrB[16 * 260];

  const int tid = threadIdx.x;
  const int b  = blockIdx.x >> 3;
  const int i0 = (blockIdx.x & 7) * 64;
  const int w = tid >> 6, lane = tid & 63, quad = lane >> 4, ln = lane & 15;

  const unsigned short* pbase = P + ((size_t)(b * LCC + i0)) * 64;
  const unsigned short* qbase = Qt + (size_t)b * DDD * 64;
  const unsigned short* tbase = Tt + (size_t)b * DDD * 64;

  f32x4 accA[4][4], accB[4][4];
#pragma unroll
  for (int a = 0; a < 4; ++a)
#pragma unroll
    for (int c = 0; c < 4; ++c) {
      accA[a][c] = (f32x4){0.f, 0.f, 0.f, 0.f};
      accB[a][c] = (f32x4){0.f, 0.f, 0.f, 0.f};
    }

#pragma unroll
  for (int ks = 0; ks < 2; ++ks) {
    bf16x8 af[4];
#pragma unroll
    for (int tm = 0; tm < 4; ++tm)
      af[tm] = *(const bf16x8*)(pbase + (tm * 16 + ln) * 64 + ks * 32 + quad * 8);
#pragma unroll
    for (int tn = 0; tn < 4; ++tn) {
      const size_t boff = ((size_t)(w * 64 + tn * 16 + ln)) * 64 + ks * 32 + quad * 8;
      bf16x8 bq = *(const bf16x8*)(qbase + boff);
      bf16x8 bt = *(const bf16x8*)(tbase + boff);
#pragma unroll
      for (int tm = 0; tm < 4; ++tm) {
        accA[tm][tn] = __builtin_amdgcn_mfma_f32_16x16x32_bf16(af[tm], bq, accA[tm][tn], 0, 0, 0);
        accB[tm][tn] = __builtin_amdgcn_mfma_f32_16x16x32_bf16(af[tm], bt, accB[tm][tn], 0, 0, 0);
      }
    }
  }

  const float* cxb = cx + (size_t)b * LCC * DDD;
  float* ob = out + (size_t)b * LCC * 1024;
  const int row = tid >> 4;   // 0..15
  const int fq  = tid & 15;

#pragma unroll
  for (int tm = 0; tm < 4; ++tm) {
    // park 16 rows x 256 cols of A and Bm (C/D-layout -> row-major)
#pragma unroll
    for (int tn = 0; tn < 4; ++tn)
#pragma unroll
      for (int r = 0; r < 4; ++r) {
        int rloc = quad * 4 + r;
        TrA[rloc * 260 + w * 64 + tn * 16 + ln] = accA[tm][tn][r];
        TrB[rloc * 260 + w * 64 + tn * 16 + ln] = accB[tm][tn][r];
      }
    __syncthreads();
    const int i = i0 + tm * 16 + row;
#pragma unroll
    for (int u = 0; u < 4; ++u) {
      int c0 = (fq + u * 16) * 4;
      float4 a  = *(const float4*)(TrA + row * 260 + c0);
      float4 bm = *(const float4*)(TrB + row * 260 + c0);
      float4 c  = *(const float4*)(cxb + (size_t)i * DDD + c0);
      nt_store4(ob + (size_t)i * 1024 + c0,       c.x, c.y, c.z, c.w);
      nt_store4(ob + (size_t)i * 1024 + 256 + c0, a.x, a.y, a.z, a.w);
      nt_store4(ob + (size_t)i * 1024 + 512 + c0, c.x*a.x, c.y*a.y, c.z*a.z, c.w*a.w);
      nt_store4(ob + (size_t)i * 1024 + 768 + c0, c.x*bm.x, c.y*bm.y, c.z*bm.z, c.w*bm.w);
    }
    __syncthreads();   // reads done before next park
  }
}

extern "C" void kernel_launch(void* const* d_in, const int* in_sizes, int n_in,
                              void* d_out, int out_size, void* d_ws, size_t ws_size,
                              hipStream_t stream) {
  const float* cx = (const float*)d_in[0];
  const float* qu = (const float*)d_in[1];
  const float* W  = (const float*)d_in[2];
  const float* Wb = (const float*)d_in[3];
  float* out = (float*)d_out;

  char* wsb = (char*)d_ws;
  unsigned short* P   = (unsigned short*)(wsb);                       // 4 MiB
  unsigned short* Et  = (unsigned short*)(wsb + (4ull << 20));        // 4 MiB
  unsigned short* Qt  = (unsigned short*)(wsb + (8ull << 20));        // 2 MiB
  unsigned short* Tt  = (unsigned short*)(wsb + (10ull << 20));       // 2 MiB
  float*          csp = (float*)(wsb + (12ull << 20));                // 128 KiB

  k1_scores<<<dim3(512), dim3(256), 0, stream>>>(cx, qu, W, Wb, P, Et, csp);
  k2_tmat  <<<dim3(512), dim3(256), 0, stream>>>(cx, qu, Et, csp, Qt, Tt);
  k3_out   <<<dim3(512), dim3(256), 0, stream>>>(cx, P, Qt, Tt, out);
}